// Round 1
// baseline (856.990 us; speedup 1.0000x reference)
//
#include <hip/hip_runtime.h>
#include <hip/hip_bf16.h>

#define NBANDS 31
#define CDIM 128
#define TDIM 2000
#define BDIM 4
#define HDIM 512
#define MDIM 8000      // B*T
#define MAXO 204
#define OPAD 208       // fc2 padded (permuted) output dim, multiple of 16
#define NGRP 124       // B*K group count

typedef __attribute__((ext_vector_type(8))) short short8;
typedef __attribute__((ext_vector_type(4))) float f32x4;
typedef __attribute__((ext_vector_type(4))) unsigned int u32x4;
typedef __bf16 bf16x8 __attribute__((ext_vector_type(8)));

__constant__ int d_bw[NBANDS]   = {2,3,3,3,3,3,3,3,3,3,3,8,8,8,8,8,8,8,8,8,8,8,8,16,16,16,16,16,16,16,17};
__constant__ int d_boff[NBANDS] = {0,2,5,8,11,14,17,20,23,26,29,32,40,48,56,64,72,80,88,96,104,112,120,128,144,160,176,192,208,224,240};

__device__ __forceinline__ unsigned short f2bf(float f) {
  unsigned int u = __float_as_uint(f);
  return (unsigned short)((u + 0x7fffu + ((u >> 16) & 1u)) >> 16);
}

__device__ __forceinline__ float fast_tanh(float x) {
  float e = __expf(2.0f * fabsf(x));
  float t = 1.0f - 2.0f / (e + 1.0f);
  return copysignf(t, x);
}

__device__ __forceinline__ float fast_sigmoid(float x) {
  return 1.0f / (1.0f + __expf(-x));
}

__device__ __forceinline__ f32x4 mfma_bf16(short8 a, short8 b, f32x4 c) {
  return __builtin_amdgcn_mfma_f32_16x16x32_bf16(
      __builtin_bit_cast(bf16x8, a), __builtin_bit_cast(bf16x8, b), c, 0, 0, 0);
}

// ---------------- stats: per (b,k) sum / sumsq over (C,T) -------------------
__global__ void k_stats(const float* __restrict__ x, float* __restrict__ wsum,
                        float* __restrict__ wsq) {
  int b = blockIdx.x >> 7;          // 512 blocks = B*C
  int c = blockIdx.x & 127;
  const float* p = x + ((size_t)(b * CDIM + c)) * (TDIM * NBANDS);
  int tk = threadIdx.x & 31;        // k index (31 used)
  int tt = threadIdx.x >> 5;        // 0..7
  float s = 0.f, sq = 0.f;
  if (tk < 31) {
    for (int t = tt; t < TDIM; t += 8) {
      float v = p[t * 31 + tk];
      s += v; sq += v * v;
    }
  }
  __shared__ float ls[256], lq[256];
  ls[threadIdx.x] = s; lq[threadIdx.x] = sq;
  __syncthreads();
  for (int off = 128; off >= 32; off >>= 1) {
    if (threadIdx.x < off) {
      ls[threadIdx.x] += ls[threadIdx.x + off];
      lq[threadIdx.x] += lq[threadIdx.x + off];
    }
    __syncthreads();
  }
  if (threadIdx.x < 31) {
    atomicAdd(&wsum[b * 31 + threadIdx.x], ls[threadIdx.x]);
    atomicAdd(&wsq [b * 31 + threadIdx.x], lq[threadIdx.x]);
  }
}

__global__ void k_finalize(const float* __restrict__ wsum, const float* __restrict__ wsq,
                           float* __restrict__ gmean, float* __restrict__ grstd) {
  int g = threadIdx.x;
  if (g < NGRP) {
    const float n = (float)(CDIM * TDIM);
    float m = wsum[g] / n;
    float v = wsq[g] / n - m * m;
    gmean[g] = m;
    grstd[g] = rsqrtf(v + 1e-5f);
  }
}

// ---------------- weight prep: fold norm affine into fc1 -------------------
__global__ void k_prep_w1(const float* __restrict__ fc1_w, const float* __restrict__ norm_w,
                          const float* __restrict__ norm_b, unsigned short* __restrict__ w1,
                          float* __restrict__ t1, float* __restrict__ t2) {
  int kn = blockIdx.x;              // k*512 + n
  int k = kn >> 9;
  int c = threadIdx.x;              // 128 threads
  float w  = fc1_w[(size_t)kn * CDIM + c];
  float nw = norm_w[k * CDIM + c];
  float nb = norm_b[k * CDIM + c];
  float wp = w * nw;
  w1[(size_t)kn * CDIM + c] = f2bf(wp);
  float s1 = wp, s2 = w * nb;
  #pragma unroll
  for (int off = 32; off >= 1; off >>= 1) {
    s1 += __shfl_down(s1, off);
    s2 += __shfl_down(s2, off);
  }
  __shared__ float r1[2], r2[2];
  if ((threadIdx.x & 63) == 0) { r1[threadIdx.x >> 6] = s1; r2[threadIdx.x >> 6] = s2; }
  __syncthreads();
  if (threadIdx.x == 0) { t1[kn] = r1[0] + r1[1]; t2[kn] = r2[0] + r2[1]; }
}

// fc2 weights: permute rows so GLU pairs (a_i, g_i) are adjacent; pad to OPAD rows.
__global__ void k_prep_w2(const float* __restrict__ fc2_w, const float* __restrict__ fc2_b,
                          unsigned short* __restrict__ w2, float* __restrict__ b2) {
  int ko = blockIdx.x;              // k*OPAD + o
  int k = ko / OPAD;
  int o = ko - k * OPAD;
  int bw = d_bw[k];
  int O2 = 12 * bw, half = 6 * bw;
  unsigned short* dst = w2 + (size_t)ko * HDIM;
  if (o < O2) {
    int src = (o & 1) ? (half + (o >> 1)) : (o >> 1);
    const float* sp = fc2_w + ((size_t)k * MAXO + src) * HDIM;
    for (int j = threadIdx.x; j < HDIM; j += 256) dst[j] = f2bf(sp[j]);
    if (threadIdx.x == 0) b2[ko] = fc2_b[k * MAXO + src];
  } else {
    for (int j = threadIdx.x; j < HDIM; j += 256) dst[j] = 0;
    if (threadIdx.x == 0) b2[ko] = 0.f;
  }
}

// ---------------- transpose x[B,C,T,K] -> xt[K][B*T][C] bf16 ----------------
#define TTR 31
__global__ void k_transpose(const float* __restrict__ x, unsigned short* __restrict__ xt) {
  __shared__ unsigned short tile[961 * 34];   // [f = ti*31+k][ci], pad 34
  int t0 = blockIdx.x * TTR;
  int c0 = blockIdx.y * 32;
  int b  = blockIdx.z;
  int tlen = min(TTR, TDIM - t0);
  int F = tlen * 31;
  for (int ci = 0; ci < 32; ++ci) {
    const float* p = x + ((size_t)((b * CDIM + c0 + ci) * TDIM + t0)) * NBANDS;
    for (int f = threadIdx.x; f < F; f += 256)
      tile[f * 34 + ci] = f2bf(p[f]);
  }
  __syncthreads();
  int nch = F * 4;
  for (int idx = threadIdx.x; idx < nch; idx += 256) {
    int f = idx >> 2, ch = idx & 3;
    int ti = f / 31;
    int k  = f - ti * 31;
    const unsigned int* s32 = (const unsigned int*)&tile[f * 34 + ch * 8];
    u32x4 v; v.x = s32[0]; v.y = s32[1]; v.z = s32[2]; v.w = s32[3];
    size_t m = (size_t)b * TDIM + t0 + ti;
    unsigned short* d = xt + ((size_t)k * MDIM + m) * CDIM + c0 + ch * 8;
    *(u32x4*)d = v;
  }
}

// ---------------- fused GEMM: fc1 + tanh + fc2 + GLU ------------------------
__launch_bounds__(256)
__global__ void k_gemm(const unsigned short* __restrict__ xt,
                       const unsigned short* __restrict__ w1,
                       const float* __restrict__ t1, const float* __restrict__ t2,
                       const float* __restrict__ b1,
                       const unsigned short* __restrict__ w2,
                       const float* __restrict__ b2,
                       const float* __restrict__ gmean, const float* __restrict__ grstd,
                       float* __restrict__ out) {
  __shared__ unsigned short Atile[32 * 128];  // swizzled bf16, 8 KB
  __shared__ unsigned short Hs[32 * 512];     // swizzled bf16, 32 KB
  __shared__ float s_mean[32], s_rstd[32];

  int bid = blockIdx.x;
  int k = bid / 250;
  int mt = bid - k * 250;
  int m0 = mt * 32;
  int tid = threadIdx.x;
  int lane = tid & 63;
  int wv = tid >> 6;
  int col = lane & 15;
  int grp = lane >> 4;

  // --- stage A tile (32 x 128 bf16), XOR-swizzled ---
  #pragma unroll
  for (int rep = 0; rep < 2; ++rep) {
    int idx = tid + rep * 256;
    int mi = idx >> 4, c8 = idx & 15;
    const u32x4* src = (const u32x4*)(xt + ((size_t)k * MDIM + m0 + mi) * CDIM + c8 * 8);
    u32x4 v = *src;
    unsigned byte = (unsigned)(mi * 256 + c8 * 16) ^ (unsigned)((mi & 7) << 4);
    *(u32x4*)((char*)Atile + byte) = v;
  }
  if (tid < 32) {
    int g = ((m0 + tid) / 2000) * NBANDS + k;
    s_mean[tid] = gmean[g];
    s_rstd[tid] = grstd[g];
  }
  __syncthreads();

  // --- fc1: [32 x 128] @ [128 x 512] ---
  const f32x4 fzero = {0.f, 0.f, 0.f, 0.f};
  f32x4 acc[2][8];
  #pragma unroll
  for (int i = 0; i < 2; ++i)
    #pragma unroll
    for (int j = 0; j < 8; ++j) acc[i][j] = fzero;

  const unsigned short* w1k = w1 + (size_t)k * HDIM * CDIM;
  #pragma unroll
  for (int kk = 0; kk < 4; ++kk) {
    int c0 = kk * 32 + grp * 8;
    short8 afr[2];
    #pragma unroll
    for (int m2 = 0; m2 < 2; ++m2) {
      int row = m2 * 16 + col;
      unsigned byte = (unsigned)(row * 256 + c0 * 2) ^ (unsigned)((row & 7) << 4);
      afr[m2] = *(const short8*)((const char*)Atile + byte);
    }
    #pragma unroll
    for (int nt = 0; nt < 8; ++nt) {
      int n = wv * 128 + nt * 16 + col;
      short8 bfr = *(const short8*)(w1k + (size_t)n * CDIM + c0);
      acc[0][nt] = mfma_bf16(afr[0], bfr, acc[0][nt]);
      acc[1][nt] = mfma_bf16(afr[1], bfr, acc[1][nt]);
    }
  }

  // --- fc1 epilogue: norm fold + bias + tanh -> Hs (swizzled) ---
  const float* t1k = t1 + k * HDIM;
  const float* t2k = t2 + k * HDIM;
  const float* b1k = b1 + k * HDIM;
  #pragma unroll
  for (int nt = 0; nt < 8; ++nt) {
    int n = wv * 128 + nt * 16 + col;
    float c1 = t1k[n];
    float c2 = t2k[n] + b1k[n];
    #pragma unroll
    for (int m2 = 0; m2 < 2; ++m2) {
      f32x4 v = acc[m2][nt];
      #pragma unroll
      for (int r = 0; r < 4; ++r) {
        int ml = m2 * 16 + grp * 4 + r;
        float rs = s_rstd[ml];
        float hpre = rs * v[r] - rs * s_mean[ml] * c1 + c2;
        unsigned byte = (unsigned)(ml * 1024 + n * 2) ^ (unsigned)((ml & 7) << 4);
        *(unsigned short*)((char*)Hs + byte) = f2bf(fast_tanh(hpre));
      }
    }
  }
  __syncthreads();

  // --- fc2: [32 x 512] @ [512 x 12bw(padded)] with GLU-paired columns ---
  int bw = d_bw[k];
  int O2 = 12 * bw;
  int half = 6 * bw;
  int nN = (O2 + 15) >> 4;
  int TT2 = 2 * nN;
  const unsigned short* w2k = w2 + (size_t)k * OPAD * HDIM;

  f32x4 acc2[7];
  #pragma unroll
  for (int i = 0; i < 7; ++i) acc2[i] = fzero;

  for (int jj = 0; jj < 16; ++jj) {
    int j0 = jj * 32 + grp * 8;
    short8 ha[2];
    #pragma unroll
    for (int m2 = 0; m2 < 2; ++m2) {
      int row = m2 * 16 + col;
      unsigned byte = (unsigned)(row * 1024 + j0 * 2) ^ (unsigned)((row & 7) << 4);
      ha[m2] = *(const short8*)((const char*)Hs + byte);
    }
    #pragma unroll
    for (int i = 0; i < 7; ++i) {
      int tau = wv + 4 * i;
      if (tau < TT2) {
        int m2 = tau & 1, nt = tau >> 1;
        int n = nt * 16 + col;
        short8 bfr = *(const short8*)(w2k + (size_t)n * HDIM + j0);
        acc2[i] = mfma_bf16(m2 ? ha[1] : ha[0], bfr, acc2[i]);
      }
    }
  }

  // --- fc2 epilogue: bias, GLU via shfl_xor pair exchange, scatter store ---
  const float* b2k = b2 + k * OPAD;
  int boffk = d_boff[k];
  #pragma unroll
  for (int i = 0; i < 7; ++i) {
    int tau = wv + 4 * i;
    if (tau < TT2) {
      int m2 = tau & 1, nt = tau >> 1;
      int n = nt * 16 + col;
      float bias = b2k[n];
      int op = n >> 1;
      bool isA = (n & 1) == 0;
      f32x4 v = acc2[i];
      #pragma unroll
      for (int r = 0; r < 4; ++r) {
        float val = v[r] + bias;
        float other = __shfl_xor(val, 1);
        if (isA && op < half) {
          float res = val * fast_sigmoid(other);
          int m = m0 + m2 * 16 + grp * 4 + r;
          int bb = m / 2000;
          int t = m - bb * 2000;
          int rr = op / 6;
          int cc = op - rr * 6;
          out[(((size_t)bb * 257 + boffk + rr) * TDIM + t) * 6 + cc] = res;
        }
      }
    }
  }
}

extern "C" void kernel_launch(void* const* d_in, const int* in_sizes, int n_in,
                              void* d_out, int out_size, void* d_ws, size_t ws_size,
                              hipStream_t stream) {
  const float* x      = (const float*)d_in[0];
  const float* norm_w = (const float*)d_in[1];
  const float* norm_b = (const float*)d_in[2];
  const float* fc1_w  = (const float*)d_in[3];
  const float* fc1_b  = (const float*)d_in[4];
  const float* fc2_w  = (const float*)d_in[5];
  const float* fc2_b  = (const float*)d_in[6];
  float* out = (float*)d_out;
  char* ws = (char*)d_ws;

  float* wsum  = (float*)(ws);
  float* wsq   = (float*)(ws + 512);
  float* gmean = (float*)(ws + 1024);
  float* grstd = (float*)(ws + 1536);
  size_t off = 4096;
  unsigned short* xt  = (unsigned short*)(ws + off); off += (size_t)NBANDS * MDIM * CDIM * 2;
  unsigned short* w1p = (unsigned short*)(ws + off); off += (size_t)NBANDS * HDIM * CDIM * 2;
  float* t1p = (float*)(ws + off); off += (size_t)NBANDS * HDIM * 4;
  float* t2p = (float*)(ws + off); off += (size_t)NBANDS * HDIM * 4;
  unsigned short* w2p = (unsigned short*)(ws + off); off += (size_t)NBANDS * OPAD * HDIM * 2;
  float* b2p = (float*)(ws + off); off += (size_t)NBANDS * OPAD * 4;

  hipMemsetAsync(ws, 0, 1024, stream);
  hipLaunchKernelGGL(k_stats, dim3(BDIM * CDIM), dim3(256), 0, stream, x, wsum, wsq);
  hipLaunchKernelGGL(k_finalize, dim3(1), dim3(128), 0, stream, wsum, wsq, gmean, grstd);
  hipLaunchKernelGGL(k_prep_w1, dim3(NBANDS * HDIM), dim3(128), 0, stream,
                     fc1_w, norm_w, norm_b, w1p, t1p, t2p);
  hipLaunchKernelGGL(k_prep_w2, dim3(NBANDS * OPAD), dim3(256), 0, stream,
                     fc2_w, fc2_b, w2p, b2p);
  hipLaunchKernelGGL(k_transpose, dim3(65, 4, 4), dim3(256), 0, stream, x, xt);
  hipLaunchKernelGGL(k_gemm, dim3(NBANDS * 250), dim3(256), 0, stream,
                     xt, w1p, t1p, t2p, fc1_b, w2p, b2p, gmean, grstd, out);
}

// Round 2
// 377.229 us; speedup vs baseline: 2.2718x; 2.2718x over previous
//
#include <hip/hip_runtime.h>
#include <hip/hip_bf16.h>

#define NBANDS 31
#define CDIM 128
#define TDIM 2000
#define HDIM 512
#define MTOT 8000
#define MAXO 204
#define OPAD 224       // fc2 padded (permuted) output rows, multiple of 32
#define NGRP 124
#define NMT 63         // m-tiles of 128 per band
#define NWG (NBANDS * NMT)

typedef __attribute__((ext_vector_type(8))) short short8;
typedef __attribute__((ext_vector_type(4))) float f32x4;
typedef __attribute__((ext_vector_type(4))) unsigned int u32x4;
typedef __bf16 bf16x8 __attribute__((ext_vector_type(8)));

__constant__ int d_bw[NBANDS]   = {2,3,3,3,3,3,3,3,3,3,3,8,8,8,8,8,8,8,8,8,8,8,8,16,16,16,16,16,16,16,17};
__constant__ int d_boff[NBANDS] = {0,2,5,8,11,14,17,20,23,26,29,32,40,48,56,64,72,80,88,96,104,112,120,128,144,160,176,192,208,224,240};
__constant__ int d_nn16[NBANDS] = {2,3,3,3,3,3,3,3,3,3,3,6,6,6,6,6,6,6,6,6,6,6,6,12,12,12,12,12,12,12,13};
__constant__ int d_o32[NBANDS]  = {32,64,64,64,64,64,64,64,64,64,64,96,96,96,96,96,96,96,96,96,96,96,96,192,192,192,192,192,192,192,224};

__device__ __forceinline__ unsigned short f2bf(float f) {
  unsigned int u = __float_as_uint(f);
  return (unsigned short)((u + 0x7fffu + ((u >> 16) & 1u)) >> 16);
}

__device__ __forceinline__ float fast_tanh(float x) {
  float e = __expf(2.0f * fabsf(x));
  float t = 1.0f - 2.0f / (e + 1.0f);
  return copysignf(t, x);
}

__device__ __forceinline__ float fast_sigmoid(float x) {
  return 1.0f / (1.0f + __expf(-x));
}

__device__ __forceinline__ f32x4 mfma_bf16(short8 a, short8 b, f32x4 c) {
  return __builtin_amdgcn_mfma_f32_16x16x32_bf16(
      __builtin_bit_cast(bf16x8, a), __builtin_bit_cast(bf16x8, b), c, 0, 0, 0);
}

// ------------- finalize group stats -------------
__global__ void k_finalize(const float* __restrict__ wsum, const float* __restrict__ wsq,
                           float* __restrict__ gmean, float* __restrict__ grstd) {
  int g = threadIdx.x;
  if (g < NGRP) {
    const float n = (float)(CDIM * TDIM);
    float m = wsum[g] / n;
    float v = wsq[g] / n - m * m;
    gmean[g] = m;
    grstd[g] = rsqrtf(v + 1e-5f);
  }
}

// ------------- prep fc1 weights: fold norm affine, swizzle rows -------------
__global__ void k_prep_w1(const float* __restrict__ fc1_w, const float* __restrict__ norm_w,
                          const float* __restrict__ norm_b, const float* __restrict__ fc1_b,
                          unsigned short* __restrict__ w1, float* __restrict__ t1,
                          float* __restrict__ t2) {
  int kn = blockIdx.x;              // k*512 + n
  int k = kn >> 9, n = kn & 511;
  int c = threadIdx.x;              // 128 threads
  float w  = fc1_w[(size_t)kn * CDIM + c];
  float nw = norm_w[k * CDIM + c];
  float nb = norm_b[k * CDIM + c];
  float wp = w * nw;
  int byte = (2 * c) ^ ((n & 7) << 4);
  *(unsigned short*)((char*)w1 + (size_t)kn * 256 + byte) = f2bf(wp);
  float s1 = wp, s2 = w * nb;
  #pragma unroll
  for (int off = 32; off >= 1; off >>= 1) {
    s1 += __shfl_down(s1, off);
    s2 += __shfl_down(s2, off);
  }
  __shared__ float r1[2], r2[2];
  if ((threadIdx.x & 63) == 0) { r1[threadIdx.x >> 6] = s1; r2[threadIdx.x >> 6] = s2; }
  __syncthreads();
  if (threadIdx.x == 0) {
    t1[kn] = r1[0] + r1[1];
    t2[kn] = r2[0] + r2[1] + fc1_b[kn];
  }
}

// ------------- prep fc2 weights: GLU-pair permute, chunked [k][nc][o][kc], swizzled ----
__global__ void k_prep_w2(const float* __restrict__ fc2_w, const float* __restrict__ fc2_b,
                          unsigned short* __restrict__ w2, float* __restrict__ b2) {
  int ko = blockIdx.x;              // k*OPAD + o
  int k = ko / OPAD;
  int o = ko - k * OPAD;
  int bw = d_bw[k];
  int O2 = 12 * bw, hf = 6 * bw;
  int srcrow = (o & 1) ? (hf + (o >> 1)) : (o >> 1);
  bool valid = o < O2;
  const float* sp = fc2_w + ((size_t)k * MAXO + srcrow) * HDIM;
  if (threadIdx.x == 0) b2[ko] = valid ? fc2_b[k * MAXO + srcrow] : 0.f;
  for (int j = threadIdx.x; j < HDIM; j += 256) {
    int nc = j >> 7, kc = j & 127;
    unsigned short val = valid ? f2bf(sp[j]) : (unsigned short)0;
    size_t row = (size_t)(k * 4 + nc) * OPAD + o;
    *(unsigned short*)((char*)w2 + row * 256 + ((2 * kc) ^ ((o & 7) << 4))) = val;
  }
}

// ------------- transpose x[B,C,T,K] -> xt[K][8000][128] bf16, fused stats ----
__global__ void k_transpose(const float* __restrict__ x, unsigned short* __restrict__ xt,
                            float* __restrict__ wsum, float* __restrict__ wsq) {
  __shared__ unsigned short tile[248 * 128];   // 62 KB, rows staggered by 4f bytes
  __shared__ float sred[256], sqred[256];
  const int t0 = blockIdx.x * 8;
  const int b = blockIdx.y;
  const int tid = threadIdx.x;
  const float* p = x + ((size_t)b * CDIM * TDIM + t0) * NBANDS;
  float s = 0.f, sq = 0.f;
  if (tid < 248) {
    const int f = tid;
    char* row = (char*)tile + f * 256;
    const int st = 4 * f;
    #pragma unroll 4
    for (int c2 = 0; c2 < 64; ++c2) {
      float v0 = p[(size_t)c2 * 124000 + f];
      float v1 = p[(size_t)c2 * 124000 + 62000 + f];
      s += v0 + v1;
      sq += v0 * v0 + v1 * v1;
      unsigned int pk = (unsigned int)f2bf(v0) | ((unsigned int)f2bf(v1) << 16);
      *(unsigned int*)(row + ((4 * c2 + st) & 255)) = pk;
    }
  }
  sred[tid] = s; sqred[tid] = sq;
  __syncthreads();
  if (tid < 31) {
    float ss = 0.f, qs = 0.f;
    #pragma unroll
    for (int j = 0; j < 8; ++j) { ss += sred[tid + 31 * j]; qs += sqred[tid + 31 * j]; }
    atomicAdd(&wsum[b * 31 + tid], ss);
    atomicAdd(&wsq [b * 31 + tid], qs);
  }
  // write out: full 256B rows, de-staggered reads
  for (int idx = tid; idx < 248 * 16; idx += 256) {
    int f = idx >> 4, ch = idx & 15;
    const char* row = (const char*)tile + f * 256;
    const int st = 4 * f;
    u32x4 v;
    #pragma unroll
    for (int j = 0; j < 4; ++j)
      v[j] = *(const unsigned int*)(row + ((16 * ch + 4 * j + st) & 255));
    int ti = f / 31;
    int kb = f - ti * 31;
    size_t m = (size_t)b * TDIM + t0 + ti;
    *(u32x4*)(xt + ((size_t)kb * MTOT + m) * CDIM + ch * 8) = v;
  }
}

// ------------- fused GEMM: fc1 + tanh + fc2 + GLU ------------------------
__launch_bounds__(512, 2)
__global__ void k_gemm(const unsigned short* __restrict__ xt,
                       const unsigned short* __restrict__ w1p,
                       const float* __restrict__ t1p, const float* __restrict__ t2p,
                       const unsigned short* __restrict__ w2p,
                       const float* __restrict__ b2p,
                       const float* __restrict__ gmean, const float* __restrict__ grstd,
                       float* __restrict__ out) {
  extern __shared__ char lds[];
  char* const W1sA = lds;                 // 32 KB
  char* const W1sB = lds + 32768;         // 32 KB
  char* const Hs   = lds + 65536;         // 32 KB  [128 m][128 h] swizzled
  char* const W2s  = lds + 98304;         // 56 KB  [<=224 o][128 kc] swizzled

  // bijective XCD-aware swizzle (nwg = 1953)
  const int bid = blockIdx.x;
  const int qq = NWG >> 3, r8 = NWG & 7;
  const int xcd = bid & 7, ixd = bid >> 3;
  const int wg = (xcd < r8 ? xcd * (qq + 1) : r8 * (qq + 1) + (xcd - r8) * qq) + ixd;
  const int k = wg / NMT;
  const int mt = wg - k * NMT;
  const int m0 = mt * 128;

  const int tid = threadIdx.x;
  const int lane = tid & 63;
  const int wid = tid >> 6;
  const int gm = wid & 1;     // m-half (64 rows)
  const int gh = wid >> 1;    // fc1 h-group (32 h) / fc2 o-group
  const int col = lane & 15;
  const int q4 = lane >> 4;

  const int bw = d_bw[k];
  const int nn = d_nn16[k];
  const int o32 = d_o32[k];
  const int nst2 = o32 >> 5;      // 8 KB staging iters for W2 chunk
  const int half = 6 * bw;
  const int boffk = d_boff[k];

  const unsigned short* const xtk = xt + (size_t)k * MTOT * CDIM;
  const unsigned short* const w1k = w1p + (size_t)k * HDIM * CDIM;
  const unsigned short* const w2k = w2p + (size_t)k * 4 * OPAD * CDIM;

  // per-mt4 X row pointers (clamped for tail tile) + norm constants
  const unsigned short* xrp[4];
  float rs4[4], mn4[4];
  #pragma unroll
  for (int m4 = 0; m4 < 4; ++m4) {
    int mr = m0 + gm * 64 + m4 * 16 + col;
    int mc = mr < (MTOT - 1) ? mr : (MTOT - 1);
    xrp[m4] = xtk + (size_t)mc * CDIM;
    int g = (mc / 2000) * NBANDS + k;
    rs4[m4] = grstd[g];
    mn4[m4] = gmean[g];
  }

  // prologue: stage W1 chunk0 + W2 chunk0, prefetch W1 chunk1
  u32x4 stW1[4], stW2[7];
  #pragma unroll
  for (int it = 0; it < 4; ++it)
    stW1[it] = *(const u32x4*)(w1k + it * 4096 + tid * 8);
  #pragma unroll
  for (int it = 0; it < 7; ++it)
    if (it < nst2) stW2[it] = *(const u32x4*)(w2k + it * 4096 + tid * 8);
  #pragma unroll
  for (int it = 0; it < 4; ++it)
    *(u32x4*)(W1sA + it * 8192 + tid * 16) = stW1[it];
  #pragma unroll
  for (int it = 0; it < 7; ++it)
    if (it < nst2) *(u32x4*)(W2s + it * 8192 + tid * 16) = stW2[it];
  #pragma unroll
  for (int it = 0; it < 4; ++it)
    stW1[it] = *(const u32x4*)(w1k + 128 * CDIM + it * 4096 + tid * 8);

  const f32x4 fz = {0.f, 0.f, 0.f, 0.f};
  f32x4 acc2[4][4];
  #pragma unroll
  for (int a = 0; a < 4; ++a)
    #pragma unroll
    for (int b = 0; b < 4; ++b) acc2[a][b] = fz;

  __syncthreads();

  for (int nc = 0; nc < 4; ++nc) {
    char* const W1c = (nc & 1) ? W1sB : W1sA;

    // ---- fc1 (swapped operands): acc1[m4][ht] = W1_tile x X_tile ----
    f32x4 acc1[4][2];
    #pragma unroll
    for (int a = 0; a < 4; ++a) { acc1[a][0] = fz; acc1[a][1] = fz; }

    #pragma unroll
    for (int kk = 0; kk < 4; ++kk) {
      const int cb = kk * 64 + q4 * 16;
      const int hr0 = gh * 32 + col;
      const int hr1 = hr0 + 16;
      short8 wa0 = *(const short8*)(W1c + hr0 * 256 + (cb ^ ((hr0 & 7) << 4)));
      short8 wa1 = *(const short8*)(W1c + hr1 * 256 + (cb ^ ((hr1 & 7) << 4)));
      #pragma unroll
      for (int m4 = 0; m4 < 4; ++m4) {
        short8 xv = *(const short8*)(xrp[m4] + kk * 32 + q4 * 8);
        acc1[m4][0] = mfma_bf16(wa0, xv, acc1[m4][0]);
        acc1[m4][1] = mfma_bf16(wa1, xv, acc1[m4][1]);
      }
    }

    // ---- fc1 epilogue: fold norm, tanh, pack 4 h -> b64 into Hs ----
    const float* t1k = t1p + k * HDIM + nc * 128;
    const float* t2k = t2p + k * HDIM + nc * 128;
    #pragma unroll
    for (int m4 = 0; m4 < 4; ++m4) {
      const int mloc = gm * 64 + m4 * 16 + col;
      const int swz = (mloc & 7) << 4;
      const float rsm = rs4[m4], rmn = rs4[m4] * mn4[m4];
      #pragma unroll
      for (int ht = 0; ht < 2; ++ht) {
        const int hb = gh * 32 + ht * 16 + q4 * 4;
        f32x4 c1 = *(const f32x4*)(t1k + hb);
        f32x4 c2 = *(const f32x4*)(t2k + hb);
        f32x4 v = acc1[m4][ht];
        float e0 = fast_tanh(rsm * v[0] - rmn * c1[0] + c2[0]);
        float e1 = fast_tanh(rsm * v[1] - rmn * c1[1] + c2[1]);
        float e2 = fast_tanh(rsm * v[2] - rmn * c1[2] + c2[2]);
        float e3 = fast_tanh(rsm * v[3] - rmn * c1[3] + c2[3]);
        unsigned long long pk =
            (unsigned long long)f2bf(e0) | ((unsigned long long)f2bf(e1) << 16) |
            ((unsigned long long)f2bf(e2) << 32) | ((unsigned long long)f2bf(e3) << 48);
        *(unsigned long long*)(Hs + mloc * 256 + ((2 * hb) ^ swz)) = pk;
      }
    }

    // stage-ahead writes (data loaded a full phase ago)
    if (nc >= 1) {
      #pragma unroll
      for (int it = 0; it < 7; ++it)
        if (it < nst2) *(u32x4*)(W2s + it * 8192 + tid * 16) = stW2[it];
    }
    if (nc < 3) {
      char* const Wn = ((nc + 1) & 1) ? W1sB : W1sA;
      #pragma unroll
      for (int it = 0; it < 4; ++it)
        *(u32x4*)(Wn + it * 8192 + tid * 16) = stW1[it];
      const unsigned short* w2src = w2k + (size_t)(nc + 1) * OPAD * CDIM;
      #pragma unroll
      for (int it = 0; it < 7; ++it)
        if (it < nst2) stW2[it] = *(const u32x4*)(w2src + it * 4096 + tid * 8);
    }

    __syncthreads();   // Hs + W2s[nc] + W1s[nc+1] visible

    // ---- fc2 partial: acc2 += H_chunk x W2_chunk ----
    #pragma unroll
    for (int kp = 0; kp < 4; ++kp) {
      const int cb = kp * 64 + q4 * 16;
      short8 ha[4];
      #pragma unroll
      for (int m4 = 0; m4 < 4; ++m4) {
        const int mloc = gm * 64 + m4 * 16 + col;
        ha[m4] = *(const short8*)(Hs + mloc * 256 + (cb ^ ((mloc & 7) << 4)));
      }
      #pragma unroll
      for (int s = 0; s < 4; ++s) {
        const int i = gh + 4 * s;
        if (i < nn) {
          const int orow = i * 16 + col;
          short8 wb = *(const short8*)(W2s + orow * 256 + (cb ^ ((orow & 7) << 4)));
          #pragma unroll
          for (int m4 = 0; m4 < 4; ++m4)
            acc2[m4][s] = mfma_bf16(ha[m4], wb, acc2[m4][s]);
        }
      }
    }

    __syncthreads();   // fc2 done with W2s/Hs; W1s[nc+1] drained

    if (nc < 2) {
      const unsigned short* w1src = w1k + (size_t)(nc + 2) * 128 * CDIM;
      #pragma unroll
      for (int it = 0; it < 4; ++it)
        stW1[it] = *(const u32x4*)(w1src + it * 4096 + tid * 8);
    }
  }

  // ---- output epilogue: bias, GLU via shfl_xor, scatter store ----
  const float* b2k = b2p + (size_t)k * OPAD;
  #pragma unroll
  for (int s = 0; s < 4; ++s) {
    const int i = gh + 4 * s;
    if (i < nn) {
      const int o = i * 16 + col;
      const float bias = b2k[o];
      const bool isA = (o & 1) == 0;
      const int op = o >> 1;
      #pragma unroll
      for (int m4 = 0; m4 < 4; ++m4) {
        f32x4 v = acc2[m4][s];
        #pragma unroll
        for (int r2 = 0; r2 < 4; ++r2) {
          float val = v[r2] + bias;
          float other = __shfl_xor(val, 1);
          int m = m0 + gm * 64 + m4 * 16 + q4 * 4 + r2;
          if (isA && op < half && m < MTOT) {
            float res = val * fast_sigmoid(other);
            int bb = m / 2000;
            int t = m - bb * 2000;
            int orr = op / 6;
            int occ = op - orr * 6;
            out[(((size_t)bb * 257 + boffk + orr) * TDIM + t) * 6 + occ] = res;
          }
        }
      }
    }
  }
}

extern "C" void kernel_launch(void* const* d_in, const int* in_sizes, int n_in,
                              void* d_out, int out_size, void* d_ws, size_t ws_size,
                              hipStream_t stream) {
  const float* x      = (const float*)d_in[0];
  const float* norm_w = (const float*)d_in[1];
  const float* norm_b = (const float*)d_in[2];
  const float* fc1_w  = (const float*)d_in[3];
  const float* fc1_b  = (const float*)d_in[4];
  const float* fc2_w  = (const float*)d_in[5];
  const float* fc2_b  = (const float*)d_in[6];
  float* out = (float*)d_out;
  char* ws = (char*)d_ws;

  float* wsum  = (float*)(ws);
  float* wsq   = (float*)(ws + 512);
  float* gmean = (float*)(ws + 1024);
  float* grstd = (float*)(ws + 1536);
  size_t off = 4096;
  unsigned short* xtp = (unsigned short*)(ws + off); off += (size_t)NBANDS * MTOT * CDIM * 2;
  unsigned short* w1p = (unsigned short*)(ws + off); off += (size_t)NBANDS * HDIM * CDIM * 2;
  float* t1p = (float*)(ws + off); off += (size_t)NBANDS * HDIM * 4;
  float* t2p = (float*)(ws + off); off += (size_t)NBANDS * HDIM * 4;
  unsigned short* w2p = (unsigned short*)(ws + off); off += (size_t)NBANDS * 4 * OPAD * CDIM * 2;
  float* b2p = (float*)(ws + off); off += (size_t)NBANDS * OPAD * 4;

  hipMemsetAsync(ws, 0, 1024, stream);
  hipLaunchKernelGGL(k_prep_w1, dim3(NBANDS * HDIM), dim3(128), 0, stream,
                     fc1_w, norm_w, norm_b, fc1_b, w1p, t1p, t2p);
  hipLaunchKernelGGL(k_prep_w2, dim3(NBANDS * OPAD), dim3(256), 0, stream,
                     fc2_w, fc2_b, w2p, b2p);
  hipLaunchKernelGGL(k_transpose, dim3(250, 4), dim3(256), 0, stream, x, xtp, wsum, wsq);
  hipLaunchKernelGGL(k_finalize, dim3(1), dim3(128), 0, stream, wsum, wsq, gmean, grstd);

  hipFuncSetAttribute((const void*)k_gemm, hipFuncAttributeMaxDynamicSharedMemorySize, 155648);
  hipLaunchKernelGGL(k_gemm, dim3(NWG), dim3(512), 155648, stream,
                     xtp, w1p, t1p, t2p, w2p, b2p, gmean, grstd, out);
}